// Round 7
// baseline (442.030 us; speedup 1.0000x reference)
//
#include <hip/hip_runtime.h>
#include <hip/hip_bf16.h>
#include <math.h>

#define B_   4
#define N_   6
#define CIN  512
#define CT   64
#define Dd   41
#define FH   16
#define FW   44
#define NPIX 704
#define NO   105
#define NOP  128          // padded output rows (bf16 weights)
#define NXX  128
#define NYY  128
#define NZZ  1
#define TOT  (B_*NZZ*NYY*NXX)   // 65536
#define NPTS (B_*N_*Dd*NPIX)    // 692736
#define NCHUNK ((NPTS+63)/64)   // 10824

#define PK_INVALID 0xFFFFFFFFu

#define XSTRIDE 72   // bf16 elems per s_xT row
#define WSTRIDE 72   // bf16 elems per s_wd row

typedef __attribute__((ext_vector_type(8))) short short8;
typedef __attribute__((ext_vector_type(4))) float f32x4;

// ---------------- helpers ----------------

__device__ __forceinline__ unsigned short f2bf(float f) {   // RNE
    unsigned u = __float_as_uint(f);
    u += 0x7FFFu + ((u >> 16) & 1u);
    return (unsigned short)(u >> 16);
}

__device__ __forceinline__ unsigned pack_bf2(float a, float c) {
    return (unsigned)f2bf(a) | ((unsigned)f2bf(c) << 16);
}

__device__ __forceinline__ void inv3(const double* m, double* o) {
    double a=m[0],b=m[1],c=m[2],d=m[3],e=m[4],f=m[5],g=m[6],h=m[7],i=m[8];
    double A  =  (e*i - f*h);
    double Bc = -(d*i - f*g);
    double Cc =  (d*h - e*g);
    double det = a*A + b*Bc + c*Cc;
    double inv = 1.0/det;
    o[0]=A*inv;            o[1]=-(b*i - c*h)*inv;  o[2]= (b*f - c*e)*inv;
    o[3]=Bc*inv;           o[4]= (a*i - c*g)*inv;  o[5]=-(a*f - c*d)*inv;
    o[6]=Cc*inv;           o[7]=-(a*h - b*g)*inv;  o[8]= (a*e - b*d)*inv;
}

// ---------------- kernel P: prep = per-(b,n) transforms + Wd->bf16 ----------------
__global__ __launch_bounds__(256) void prep_kernel(
    const float* __restrict__ rots, const float* __restrict__ trans,
    const float* __restrict__ intrins, const float* __restrict__ post_rots,
    const float* __restrict__ post_trans, const float* __restrict__ Wd,
    double* __restrict__ tf, unsigned short* __restrict__ WdB)
{
    int idx = blockIdx.x * 256 + threadIdx.x;
    if (idx < NOP*CIN) {
        int o = idx / CIN;
        WdB[idx] = (o < NO) ? f2bf(Wd[idx]) : (unsigned short)0;
    }
    if (blockIdx.x == 0 && threadIdx.x < B_*N_) {
        int bn = threadIdx.x;
        double k[9], pr[9], r[9], ik[9], ipr[9], c[9];
        for (int i=0;i<9;i++) { k[i]=intrins[bn*9+i]; pr[i]=post_rots[bn*9+i]; r[i]=rots[bn*9+i]; }
        inv3(k, ik);
        inv3(pr, ipr);
        for (int i=0;i<3;i++)
            for (int j=0;j<3;j++) {
                double s = 0.0;
                for (int kk=0;kk<3;kk++) s += r[i*3+kk]*ik[kk*3+j];
                c[i*3+j] = s;
            }
        double* o = tf + bn*24;
        for (int i=0;i<9;i++) o[i]   = c[i];
        for (int i=0;i<9;i++) o[9+i] = ipr[i];
        for (int i=0;i<3;i++) o[18+i] = (double)trans[bn*3+i];
        for (int i=0;i<3;i++) o[21+i] = (double)post_trans[bn*3+i];
    }
}

// ---------------- kernel G: bf16 MFMA GEMM ----------------
// grid = 24 bn x 11 pixtiles x 4 osplits = 1056 blocks; block = 256 thr = 4 waves.
// Block computes 64 pixels x 32 outputs (otiles {2s, 2s+1}).
__global__ __launch_bounds__(256) void gemm_kernel(
    const float* __restrict__ x, const unsigned short* __restrict__ WdB,
    const float* __restrict__ bd,
    float* __restrict__ featD, float* __restrict__ featB)
{
    __shared__ unsigned short s_xT[64*XSTRIDE];   // [pix][k] bf16   9.2 KB
    __shared__ unsigned short s_wd[32*WSTRIDE];   // [o][k]  bf16    4.6 KB

    const int t    = threadIdx.x;
    const int l    = t & 63;
    const int wv   = t >> 6;
    const int col  = l & 15;
    const int quad = l >> 4;
    const int bn   = blockIdx.x / 44;
    const int r    = blockIdx.x % 44;
    const int tile = r % 11;
    const int s    = r / 11;          // osplit 0..3
    const int pix0 = tile * 64;

    f32x4 acc[2];
    acc[0] = (f32x4){0.f,0.f,0.f,0.f};
    acc[1] = (f32x4){0.f,0.f,0.f,0.f};

    const float* xb = x + (size_t)bn * CIN * NPIX + pix0;
    const unsigned* wsrc = (const unsigned*)WdB + (size_t)(s*32)*(CIN/2);

    for (int k0 = 0; k0 < CIN; k0 += 64) {
        // ---- stage x tile (64k x 64pix fp32 -> bf16, transposed [pix][k]) ----
        {
            unsigned pkx[8];
            #pragma unroll
            for (int j = 0; j < 8; j++) {
                float a = xb[(size_t)(k0 + wv*16 + 2*j    )*NPIX + l];
                float c = xb[(size_t)(k0 + wv*16 + 2*j + 1)*NPIX + l];
                pkx[j] = pack_bf2(a, c);
            }
            unsigned* dst = (unsigned*)&s_xT[l*XSTRIDE + wv*16];
            *(uint4*)(dst + 0) = make_uint4(pkx[0],pkx[1],pkx[2],pkx[3]);
            *(uint4*)(dst + 4) = make_uint4(pkx[4],pkx[5],pkx[6],pkx[7]);
        }
        // ---- stage Wd tile (32 o-rows x 64 k) ----
        {
            uint4 v = *(const uint4*)(wsrc + (size_t)(t>>3)*(CIN/2) + (k0>>1) + (t&7)*4);
            *(uint4*)&s_wd[(t>>3)*WSTRIDE + (t&7)*8] = v;
        }
        __syncthreads();

        #pragma unroll
        for (int ks = 0; ks < 2; ks++) {
            short8 bfr = *(const short8*)&s_xT[(wv*16 + col)*XSTRIDE + quad*8 + ks*32];
            #pragma unroll
            for (int j = 0; j < 2; j++) {
                short8 afr = *(const short8*)&s_wd[(j*16 + col)*WSTRIDE + quad*8 + ks*32];
                acc[j] = __builtin_amdgcn_mfma_f32_16x16x32_bf16(afr, bfr, acc[j], 0, 0, 0);
            }
        }
        __syncthreads();
    }

    // ---- epilogue: D layout row=(quad*4+r), col=lane&15 ----
    const int pix = pix0 + wv*16 + col;
    #pragma unroll
    for (int j = 0; j < 2; j++) {
        #pragma unroll
        for (int rr = 0; rr < 4; rr++) {
            int o = (2*s + j)*16 + quad*4 + rr;
            if (o < Dd) {
                featD[(size_t)(bn*Dd + o)*NPIX + pix] = acc[j][rr] + bd[o];
            } else if (o < NO) {
                featB[((size_t)(bn*NPIX + pix))*CT + (o - Dd)] = acc[j][rr] + bd[o];
            }
        }
    }
}

// ---------------- kernel S: softmax + geometry ----------------
// grid = 24 x 11 = 264 blocks, 64 threads; thread owns one pixel.
__global__ __launch_bounds__(64) void sm_geom_kernel(
    const float* __restrict__ featD, const double* __restrict__ tf,
    float* __restrict__ w_arr, unsigned* __restrict__ pk_arr,
    int* __restrict__ hist)
{
    __shared__ double s_tf[24];
    const int t    = threadIdx.x;
    const int bn   = blockIdx.x / 11;
    const int pix  = (blockIdx.x % 11)*64 + t;
    const int b    = bn / N_;

    if (t < 24) s_tf[t] = tf[bn*24 + t];
    __syncthreads();

    // ---- softmax over 41 depth logits (registers) ----
    const float* fbase = featD + (size_t)bn*Dd*NPIX + pix;
    float fv[Dd];
    #pragma unroll
    for (int d = 0; d < Dd; d++) fv[d] = fbase[(size_t)d*NPIX];
    float mm = fv[0];
    #pragma unroll
    for (int d = 1; d < Dd; d++) mm = fmaxf(mm, fv[d]);
    float ssum = 0.0f;
    #pragma unroll
    for (int d = 0; d < Dd; d++) { fv[d] = expf(fv[d] - mm); ssum += fv[d]; }
    const float sinv = 1.0f / ssum;

    // ---- per-pixel linear f64 coefficients: s(fz) = qz(fz)*u(fz) + t ----
    const int hh = pix / FW, ww = pix % FW;
    const double fx = (double)((float)(ww * (703.0/43.0)));
    const double fy = (double)((float)(hh * 17.0));
    const double px = fx - s_tf[21], py = fy - s_tf[22], mz = -s_tf[23];
    const double qx0 = s_tf[ 9]*px + s_tf[10]*py + s_tf[11]*mz, qx1 = s_tf[11];
    const double qy0 = s_tf[12]*px + s_tf[13]*py + s_tf[14]*mz, qy1 = s_tf[14];
    const double qz0 = s_tf[15]*px + s_tf[16]*py + s_tf[17]*mz, qz1 = s_tf[17];
    const double ux0 = s_tf[0]*qx0 + s_tf[1]*qy0 + s_tf[2], ux1 = s_tf[0]*qx1 + s_tf[1]*qy1;
    const double uy0 = s_tf[3]*qx0 + s_tf[4]*qy0 + s_tf[5], uy1 = s_tf[3]*qx1 + s_tf[4]*qy1;
    const double uz0 = s_tf[6]*qx0 + s_tf[7]*qy0 + s_tf[8], uz1 = s_tf[6]*qx1 + s_tf[7]*qy1;
    const double t0 = s_tf[18], t1 = s_tf[19], t2 = s_tf[20];

    const double DXD = (double)0.8f;
    const double LOX = (double)(-50.8f) - DXD*0.5;
    const double LOY = LOX;
    const double DZD = 20.0;
    const double LOZ = -10.0;

    const unsigned pix_id = (unsigned)(bn*NPIX + pix);

    #pragma unroll
    for (int d = 0; d < Dd; d++) {
        double fz = 4.0 + (double)d;
        double qz = qz0 + qz1*fz;
        double sx = qz*(ux0 + ux1*fz) + t0;
        double sy = qz*(uy0 + uy1*fz) + t1;
        double sz = qz*(uz0 + uz1*fz) + t2;
        int gx = (int)((sx - LOX) / DXD);
        int gy = (int)((sy - LOY) / DXD);
        int gz = (int)((sz - LOZ) / DZD);
        bool kept = (gx>=0) & (gx<NXX) & (gy>=0) & (gy<NYY) & (gz>=0) & (gz<NZZ);
        int vox = (((b*NZZ + gz)*NYY + gy)*NXX + gx);
        int pt  = (bn*Dd + d)*NPIX + pix;
        w_arr[pt]  = fv[d] * sinv;
        pk_arr[pt] = kept ? (((unsigned)vox << 15) | pix_id) : PK_INVALID;
        if (kept) atomicAdd(&hist[vox], 1);
    }
}

// ---------------- kernel C: exclusive scan over 65536 bins -> cursor ----------------
__global__ __launch_bounds__(1024) void scan_kernel(const int* __restrict__ hist,
                                                    int* __restrict__ cursor) {
    __shared__ int s[1024];
    const int t = threadIdx.x;
    const int CHUNK = TOT / 1024;   // 64
    int base_idx = t * CHUNK;
    int sum = 0;
    int local[64];
    #pragma unroll 8
    for (int j=0;j<CHUNK;j++) { local[j] = hist[base_idx+j]; sum += local[j]; }
    s[t] = sum;
    __syncthreads();
    for (int off=1; off<1024; off<<=1) {
        int v = (t >= off) ? s[t-off] : 0;
        __syncthreads();
        s[t] += v;
        __syncthreads();
    }
    int run = (t==0) ? 0 : s[t-1];
    #pragma unroll 8
    for (int j=0;j<CHUNK;j++) {
        cursor[base_idx+j] = run;
        run += local[j];
    }
}

// ---------------- kernel D: scatter packed records into sorted order ----------------
__global__ __launch_bounds__(256) void scatter_idx_kernel(
    const unsigned* __restrict__ pk_arr, const float* __restrict__ w_arr,
    int* __restrict__ cursor, unsigned* __restrict__ spk,
    float* __restrict__ sw)
{
    int pt = blockIdx.x * 256 + threadIdx.x;
    if (pt >= NPTS) return;
    unsigned pk = pk_arr[pt];
    if (pk != PK_INVALID) {
        int v = pk >> 15;
        int pos = atomicAdd(&cursor[v], 1);
        spk[pos] = pk;
        sw[pos]  = w_arr[pt];
    }
}

// ---------------- kernel E: balanced segmented gather -> scat[vox][ct] ----------------
__global__ __launch_bounds__(256) void gather_kernel(
    const unsigned* __restrict__ spk, const float* __restrict__ sw,
    const int* __restrict__ cursor, const float* __restrict__ featB,
    float* __restrict__ scat)
{
    const int t  = threadIdx.x;
    const int wv = t >> 6;
    const int l  = t & 63;
    const int chunk = blockIdx.x * 4 + wv;
    const int base  = chunk * 64;
    const int Np = cursor[TOT-1];          // total valid points
    if (base >= Np) return;
    int cnt = Np - base; if (cnt > 64) cnt = 64;

    unsigned pk = 0; float w = 0.0f;
    if (l < cnt) { pk = spk[base + l]; w = sw[base + l]; }
    unsigned pkm = __shfl(pk, (l == 0) ? 0 : (l - 1));
    unsigned long long starts =
        __ballot((l > 0) && (l < cnt) && ((pk >> 15) != (pkm >> 15)));

    unsigned long long m = starts;
    int rs = 0;
    while (rs < cnt) {
        int re = m ? (__ffsll((unsigned long long)m) - 1) : cnt;
        if (m) m &= m - 1;
        float acc = 0.0f;
        for (int j = rs; j < re; j++) {
            unsigned pkj = __shfl(pk, j);
            float    wj  = __shfl(w, j);
            unsigned id  = pkj & 0x7FFFu;
            acc += wj * featB[(size_t)id * CT + l];
        }
        unsigned vrun = __shfl(pk, rs) >> 15;
        float* dst = scat + (size_t)vrun * CT + l;
        if (rs == 0 || re == cnt) {
            unsafeAtomicAdd(dst, acc);      // run may continue in adjacent chunk
        } else {
            *dst = acc;                     // voxel wholly owned by this chunk
        }
        rs = re;
    }
}

// ---------------- kernel F: transpose (b,pix,ct) -> (b,ct,pix) ----------------
__global__ __launch_bounds__(256) void transpose_k(const float* __restrict__ scat,
                                                   float* __restrict__ out) {
    __shared__ float tile[64][65];
    int b  = blockIdx.x >> 8;
    int t0 = (blockIdx.x & 255) * 64;
    const float* src = scat + (size_t)b * (NYY*NXX) * CT;
    #pragma unroll
    for (int i=0;i<16;i++) {
        int idx = threadIdx.x + i*256;
        int p = idx >> 6, c = idx & 63;
        tile[p][c] = src[(size_t)(t0+p)*CT + c];
    }
    __syncthreads();
    float* dst = out + (size_t)b * CT * (NYY*NXX);
    #pragma unroll
    for (int i=0;i<16;i++) {
        int idx = threadIdx.x + i*256;
        int c = idx >> 6, p = idx & 63;
        dst[(size_t)c*(NYY*NXX) + t0 + p] = tile[p][c];
    }
}

// ---------------- launcher ----------------
extern "C" void kernel_launch(void* const* d_in, const int* in_sizes, int n_in,
                              void* d_out, int out_size, void* d_ws, size_t ws_size,
                              hipStream_t stream) {
    const float* x          = (const float*)d_in[0];
    const float* rots       = (const float*)d_in[1];
    const float* trans      = (const float*)d_in[2];
    const float* intrins    = (const float*)d_in[3];
    const float* post_rots  = (const float*)d_in[4];
    const float* post_trans = (const float*)d_in[5];
    const float* Wd         = (const float*)d_in[6];
    const float* bd         = (const float*)d_in[7];
    float* out = (float*)d_out;

    char* ws = (char*)d_ws;
    float*          featB  = (float*)ws;          ws += (size_t)B_*N_*NPIX*CT*4;   // 4.33 MB
    float*          featD  = (float*)ws;          ws += (size_t)NPTS*4;            // 2.77 MB (aliased by spk later)
    unsigned*       pk_arr = (unsigned*)ws;       ws += (size_t)NPTS*4;            // 2.77 MB
    float*          w_arr  = (float*)ws;          ws += (size_t)NPTS*4;            // 2.77 MB
    float*          sw     = (float*)ws;          ws += (size_t)NPTS*4;            // 2.77 MB
    float*          scat   = (float*)ws;          ws += (size_t)TOT*CT*4;          // 16.78 MB
    int*            hist   = (int*)ws;            ws += (size_t)TOT*4;             // 0.26 MB
    int*            cursor = (int*)ws;            ws += (size_t)TOT*4;             // 0.26 MB
    double*         tf     = (double*)ws;         ws += (size_t)B_*N_*24*8;        // 4.6 KB
    unsigned short* WdB    = (unsigned short*)ws; ws += (size_t)NOP*CIN*2;         // 0.13 MB
    unsigned*       spk    = (unsigned*)featD;    // alias: featD consumed before scatter

    hipMemsetAsync(scat, 0, (size_t)TOT*CT*4, stream);
    hipMemsetAsync(hist, 0, (size_t)TOT*4, stream);
    prep_kernel<<<(NOP*CIN+255)/256, 256, 0, stream>>>(rots, trans, intrins, post_rots,
                                                       post_trans, Wd, tf, WdB);
    gemm_kernel<<<B_*N_*44, 256, 0, stream>>>(x, WdB, bd, featD, featB);
    sm_geom_kernel<<<B_*N_*11, 64, 0, stream>>>(featD, tf, w_arr, pk_arr, hist);
    scan_kernel<<<1, 1024, 0, stream>>>(hist, cursor);
    scatter_idx_kernel<<<(NPTS+255)/256, 256, 0, stream>>>(pk_arr, w_arr, cursor, spk, sw);
    gather_kernel<<<(NCHUNK+3)/4, 256, 0, stream>>>(spk, sw, cursor, featB, scat);
    transpose_k<<<B_*(NYY*NXX/64), 256, 0, stream>>>(scat, out);
}

// Round 8
// 315.174 us; speedup vs baseline: 1.4025x; 1.4025x over previous
//
#include <hip/hip_runtime.h>
#include <hip/hip_bf16.h>
#include <math.h>

#define B_   4
#define N_   6
#define CIN  512
#define CT   64
#define Dd   41
#define FH   16
#define FW   44
#define NPIX 704
#define NO   105
#define NOP  128          // padded output rows (bf16 weights)
#define DSTR 48           // featD per-pixel stride
#define NXX  128
#define NYY  128
#define NZZ  1
#define TOT  (B_*NZZ*NYY*NXX)   // 65536
#define NPTS (B_*N_*Dd*NPIX)    // 692736
#define NCHUNK ((NPTS+63)/64)   // 10824

#define PK_INVALID 0xFFFFFFFFu

#define XSTRIDE 72   // bf16 elems per s_xT row
#define WSTRIDE 72   // bf16 elems per s_wd row

typedef __attribute__((ext_vector_type(8))) short short8;
typedef __attribute__((ext_vector_type(4))) float f32x4;

// ---------------- helpers ----------------

__device__ __forceinline__ unsigned short f2bf(float f) {   // RNE
    unsigned u = __float_as_uint(f);
    u += 0x7FFFu + ((u >> 16) & 1u);
    return (unsigned short)(u >> 16);
}

__device__ __forceinline__ unsigned pack_bf2(float a, float c) {
    return (unsigned)f2bf(a) | ((unsigned)f2bf(c) << 16);
}

__device__ __forceinline__ void inv3(const double* m, double* o) {
    double a=m[0],b=m[1],c=m[2],d=m[3],e=m[4],f=m[5],g=m[6],h=m[7],i=m[8];
    double A  =  (e*i - f*h);
    double Bc = -(d*i - f*g);
    double Cc =  (d*h - e*g);
    double det = a*A + b*Bc + c*Cc;
    double inv = 1.0/det;
    o[0]=A*inv;            o[1]=-(b*i - c*h)*inv;  o[2]= (b*f - c*e)*inv;
    o[3]=Bc*inv;           o[4]= (a*i - c*g)*inv;  o[5]=-(a*f - c*d)*inv;
    o[6]=Cc*inv;           o[7]=-(a*h - b*g)*inv;  o[8]= (a*e - b*d)*inv;
}

// ---------------- kernel P: prep = per-(b,n) transforms + Wd->bf16 ----------------
__global__ __launch_bounds__(256) void prep_kernel(
    const float* __restrict__ rots, const float* __restrict__ trans,
    const float* __restrict__ intrins, const float* __restrict__ post_rots,
    const float* __restrict__ post_trans, const float* __restrict__ Wd,
    double* __restrict__ tf, unsigned short* __restrict__ WdB)
{
    int idx = blockIdx.x * 256 + threadIdx.x;
    if (idx < NOP*CIN) {
        int o = idx / CIN;
        WdB[idx] = (o < NO) ? f2bf(Wd[idx]) : (unsigned short)0;
    }
    if (blockIdx.x == 0 && threadIdx.x < B_*N_) {
        int bn = threadIdx.x;
        double k[9], pr[9], r[9], ik[9], ipr[9], c[9];
        for (int i=0;i<9;i++) { k[i]=intrins[bn*9+i]; pr[i]=post_rots[bn*9+i]; r[i]=rots[bn*9+i]; }
        inv3(k, ik);
        inv3(pr, ipr);
        for (int i=0;i<3;i++)
            for (int j=0;j<3;j++) {
                double s = 0.0;
                for (int kk=0;kk<3;kk++) s += r[i*3+kk]*ik[kk*3+j];
                c[i*3+j] = s;
            }
        double* o = tf + bn*24;
        for (int i=0;i<9;i++) o[i]   = c[i];
        for (int i=0;i<9;i++) o[9+i] = ipr[i];
        for (int i=0;i<3;i++) o[18+i] = (double)trans[bn*3+i];
        for (int i=0;i<3;i++) o[21+i] = (double)post_trans[bn*3+i];
    }
}

// ---------------- kernel G: bf16 MFMA GEMM ----------------
// grid = 24 bn x 11 pixtiles x 4 osplits = 1056 blocks; block = 256 thr = 4 waves.
// Block computes 64 pixels x 32 outputs (otiles {2s, 2s+1}).
__global__ __launch_bounds__(256) void gemm_kernel(
    const float* __restrict__ x, const unsigned short* __restrict__ WdB,
    const float* __restrict__ bd,
    float* __restrict__ featD, float* __restrict__ featB)
{
    __shared__ unsigned short s_xT[64*XSTRIDE];   // [pix][k] bf16   9.2 KB
    __shared__ unsigned short s_wd[32*WSTRIDE];   // [o][k]  bf16    4.6 KB

    const int t    = threadIdx.x;
    const int l    = t & 63;
    const int wv   = t >> 6;
    const int col  = l & 15;
    const int quad = l >> 4;
    const int bn   = blockIdx.x / 44;
    const int r    = blockIdx.x % 44;
    const int tile = r % 11;
    const int s    = r / 11;          // osplit 0..3
    const int pix0 = tile * 64;

    f32x4 acc[2];
    acc[0] = (f32x4){0.f,0.f,0.f,0.f};
    acc[1] = (f32x4){0.f,0.f,0.f,0.f};

    const float* xb = x + (size_t)bn * CIN * NPIX + pix0;
    const unsigned* wsrc = (const unsigned*)WdB + (size_t)(s*32)*(CIN/2);

    for (int k0 = 0; k0 < CIN; k0 += 64) {
        // ---- stage x tile (64k x 64pix fp32 -> bf16, transposed [pix][k]) ----
        {
            unsigned pkx[8];
            #pragma unroll
            for (int j = 0; j < 8; j++) {
                float a = xb[(size_t)(k0 + wv*16 + 2*j    )*NPIX + l];
                float c = xb[(size_t)(k0 + wv*16 + 2*j + 1)*NPIX + l];
                pkx[j] = pack_bf2(a, c);
            }
            unsigned* dst = (unsigned*)&s_xT[l*XSTRIDE + wv*16];
            *(uint4*)(dst + 0) = make_uint4(pkx[0],pkx[1],pkx[2],pkx[3]);
            *(uint4*)(dst + 4) = make_uint4(pkx[4],pkx[5],pkx[6],pkx[7]);
        }
        // ---- stage Wd tile (32 o-rows x 64 k) ----
        {
            uint4 v = *(const uint4*)(wsrc + (size_t)(t>>3)*(CIN/2) + (k0>>1) + (t&7)*4);
            *(uint4*)&s_wd[(t>>3)*WSTRIDE + (t&7)*8] = v;
        }
        __syncthreads();

        #pragma unroll
        for (int ks = 0; ks < 2; ks++) {
            short8 bfr = *(const short8*)&s_xT[(wv*16 + col)*XSTRIDE + quad*8 + ks*32];
            #pragma unroll
            for (int j = 0; j < 2; j++) {
                short8 afr = *(const short8*)&s_wd[(j*16 + col)*WSTRIDE + quad*8 + ks*32];
                acc[j] = __builtin_amdgcn_mfma_f32_16x16x32_bf16(afr, bfr, acc[j], 0, 0, 0);
            }
        }
        __syncthreads();
    }

    // ---- epilogue: D layout row=(quad*4+rr), col=lane&15 ----
    const int pix = pix0 + wv*16 + col;
    const size_t prow = (size_t)(bn*NPIX + pix);
    #pragma unroll
    for (int j = 0; j < 2; j++) {
        #pragma unroll
        for (int rr = 0; rr < 4; rr++) {
            int o = (2*s + j)*16 + quad*4 + rr;
            if (o < Dd) {
                featD[prow*DSTR + o] = acc[j][rr] + bd[o];
            } else if (o < NO) {
                featB[prow*CT + (o - Dd)] = acc[j][rr] + bd[o];
            }
        }
    }
}

// ---------------- kernel S: softmax + geometry, wave per pixel ----------------
// grid = 24*176 = 4224 blocks x 256 thr; block = 4 waves = 4 pixels; lane = depth.
__global__ __launch_bounds__(256) void sm_geom_kernel(
    const float* __restrict__ featD, const double* __restrict__ tf,
    float* __restrict__ w_arr, unsigned* __restrict__ pk_arr,
    int* __restrict__ hist)
{
    __shared__ double s_tf[24];
    const int t   = threadIdx.x;
    const int l   = t & 63;
    const int wv  = t >> 6;
    const int bn  = blockIdx.x / 176;           // 176 blocks per bn (704/4)
    const int pix = (blockIdx.x % 176)*4 + wv;
    const int b   = bn / N_;

    if (t < 24) s_tf[t] = tf[bn*24 + t];
    __syncthreads();

    const size_t prow = (size_t)(bn*NPIX + pix);

    // ---- softmax across lanes (d = lane, 41 active) ----
    float logit = (l < Dd) ? featD[prow*DSTR + l] : -3.0e38f;
    float mm = logit;
    #pragma unroll
    for (int off = 32; off > 0; off >>= 1) mm = fmaxf(mm, __shfl_xor(mm, off));
    float e = (l < Dd) ? expf(logit - mm) : 0.0f;
    float ssum = e;
    #pragma unroll
    for (int off = 32; off > 0; off >>= 1) ssum += __shfl_xor(ssum, off);
    const float wgt = e / ssum;

    // ---- per-pixel linear f64 coefficients (wave-uniform) ----
    const int hh = pix / FW, ww = pix % FW;
    const double fx = (double)((float)(ww * (703.0/43.0)));
    const double fy = (double)((float)(hh * 17.0));
    const double px = fx - s_tf[21], py = fy - s_tf[22], mz = -s_tf[23];
    const double qx0 = s_tf[ 9]*px + s_tf[10]*py + s_tf[11]*mz, qx1 = s_tf[11];
    const double qy0 = s_tf[12]*px + s_tf[13]*py + s_tf[14]*mz, qy1 = s_tf[14];
    const double qz0 = s_tf[15]*px + s_tf[16]*py + s_tf[17]*mz, qz1 = s_tf[17];
    const double ux0 = s_tf[0]*qx0 + s_tf[1]*qy0 + s_tf[2], ux1 = s_tf[0]*qx1 + s_tf[1]*qy1;
    const double uy0 = s_tf[3]*qx0 + s_tf[4]*qy0 + s_tf[5], uy1 = s_tf[3]*qx1 + s_tf[4]*qy1;
    const double uz0 = s_tf[6]*qx0 + s_tf[7]*qy0 + s_tf[8], uz1 = s_tf[6]*qx1 + s_tf[7]*qy1;
    const double t0 = s_tf[18], t1 = s_tf[19], t2 = s_tf[20];

    const double DXD = (double)0.8f;
    const double LOX = (double)(-50.8f) - DXD*0.5;
    const double LOY = LOX;
    const double DZD = 20.0;
    const double LOZ = -10.0;

    if (l < Dd) {
        const int d = l;
        double fz = 4.0 + (double)d;
        double qz = qz0 + qz1*fz;
        double sx = qz*(ux0 + ux1*fz) + t0;
        double sy = qz*(uy0 + uy1*fz) + t1;
        double sz = qz*(uz0 + uz1*fz) + t2;
        int gx = (int)((sx - LOX) / DXD);
        int gy = (int)((sy - LOY) / DXD);
        int gz = (int)((sz - LOZ) / DZD);
        bool kept = (gx>=0) & (gx<NXX) & (gy>=0) & (gy<NYY) & (gz>=0) & (gz<NZZ);
        int vox = (((b*NZZ + gz)*NYY + gy)*NXX + gx);
        size_t pt = prow*Dd + d;                       // pixel-major point order
        w_arr[pt]  = wgt;
        pk_arr[pt] = kept ? (((unsigned)vox << 15) | (unsigned)prow) : PK_INVALID;
        if (kept) atomicAdd(&hist[vox], 1);
    }
}

// ---------------- kernel C: exclusive scan over 65536 bins -> cursor ----------------
__global__ __launch_bounds__(1024) void scan_kernel(const int* __restrict__ hist,
                                                    int* __restrict__ cursor) {
    __shared__ int s[1024];
    const int t = threadIdx.x;
    const int CHUNK = TOT / 1024;   // 64
    int base_idx = t * CHUNK;
    int sum = 0;
    int local[64];
    #pragma unroll 8
    for (int j=0;j<CHUNK;j++) { local[j] = hist[base_idx+j]; sum += local[j]; }
    s[t] = sum;
    __syncthreads();
    for (int off=1; off<1024; off<<=1) {
        int v = (t >= off) ? s[t-off] : 0;
        __syncthreads();
        s[t] += v;
        __syncthreads();
    }
    int run = (t==0) ? 0 : s[t-1];
    #pragma unroll 8
    for (int j=0;j<CHUNK;j++) {
        cursor[base_idx+j] = run;
        run += local[j];
    }
}

// ---------------- kernel D: scatter packed records into sorted order ----------------
__global__ __launch_bounds__(256) void scatter_idx_kernel(
    const unsigned* __restrict__ pk_arr, const float* __restrict__ w_arr,
    int* __restrict__ cursor, unsigned* __restrict__ spk,
    float* __restrict__ sw)
{
    int pt = blockIdx.x * 256 + threadIdx.x;
    if (pt >= NPTS) return;
    unsigned pk = pk_arr[pt];
    if (pk != PK_INVALID) {
        int v = pk >> 15;
        int pos = atomicAdd(&cursor[v], 1);
        spk[pos] = pk;
        sw[pos]  = w_arr[pt];
    }
}

// ---------------- kernel E: balanced segmented gather -> scat[vox][ct] ----------------
__global__ __launch_bounds__(256) void gather_kernel(
    const unsigned* __restrict__ spk, const float* __restrict__ sw,
    const int* __restrict__ cursor, const float* __restrict__ featB,
    float* __restrict__ scat)
{
    const int t  = threadIdx.x;
    const int wv = t >> 6;
    const int l  = t & 63;
    const int chunk = blockIdx.x * 4 + wv;
    const int base  = chunk * 64;
    const int Np = cursor[TOT-1];          // total valid points
    if (base >= Np) return;
    int cnt = Np - base; if (cnt > 64) cnt = 64;

    unsigned pk = 0; float w = 0.0f;
    if (l < cnt) { pk = spk[base + l]; w = sw[base + l]; }
    unsigned pkm = __shfl(pk, (l == 0) ? 0 : (l - 1));
    unsigned long long starts =
        __ballot((l > 0) && (l < cnt) && ((pk >> 15) != (pkm >> 15)));

    unsigned long long m = starts;
    int rs = 0;
    while (rs < cnt) {
        int re = m ? (__ffsll((unsigned long long)m) - 1) : cnt;
        if (m) m &= m - 1;
        float acc = 0.0f;
        for (int j = rs; j < re; j++) {
            unsigned pkj = __shfl(pk, j);
            float    wj  = __shfl(w, j);
            unsigned id  = pkj & 0x7FFFu;
            acc += wj * featB[(size_t)id * CT + l];
        }
        unsigned vrun = __shfl(pk, rs) >> 15;
        float* dst = scat + (size_t)vrun * CT + l;
        if (rs == 0 || re == cnt) {
            unsafeAtomicAdd(dst, acc);      // run may continue in adjacent chunk
        } else {
            *dst = acc;                     // voxel wholly owned by this chunk
        }
        rs = re;
    }
}

// ---------------- kernel F: transpose (b,pix,ct) -> (b,ct,pix) ----------------
__global__ __launch_bounds__(256) void transpose_k(const float* __restrict__ scat,
                                                   float* __restrict__ out) {
    __shared__ float tile[64][65];
    int b  = blockIdx.x >> 8;
    int t0 = (blockIdx.x & 255) * 64;
    const float* src = scat + (size_t)b * (NYY*NXX) * CT;
    #pragma unroll
    for (int i=0;i<16;i++) {
        int idx = threadIdx.x + i*256;
        int p = idx >> 6, c = idx & 63;
        tile[p][c] = src[(size_t)(t0+p)*CT + c];
    }
    __syncthreads();
    float* dst = out + (size_t)b * CT * (NYY*NXX);
    #pragma unroll
    for (int i=0;i<16;i++) {
        int idx = threadIdx.x + i*256;
        int c = idx >> 6, p = idx & 63;
        dst[(size_t)c*(NYY*NXX) + t0 + p] = tile[p][c];
    }
}

// ---------------- launcher ----------------
extern "C" void kernel_launch(void* const* d_in, const int* in_sizes, int n_in,
                              void* d_out, int out_size, void* d_ws, size_t ws_size,
                              hipStream_t stream) {
    const float* x          = (const float*)d_in[0];
    const float* rots       = (const float*)d_in[1];
    const float* trans      = (const float*)d_in[2];
    const float* intrins    = (const float*)d_in[3];
    const float* post_rots  = (const float*)d_in[4];
    const float* post_trans = (const float*)d_in[5];
    const float* Wd         = (const float*)d_in[6];
    const float* bd         = (const float*)d_in[7];
    float* out = (float*)d_out;

    char* ws = (char*)d_ws;
    float*          featB  = (float*)ws;          ws += (size_t)B_*N_*NPIX*CT*4;    // 4.33 MB
    float*          featD  = (float*)ws;          ws += (size_t)B_*N_*NPIX*DSTR*4;  // 3.25 MB (aliased by spk)
    unsigned*       pk_arr = (unsigned*)ws;       ws += (size_t)NPTS*4;             // 2.77 MB
    float*          w_arr  = (float*)ws;          ws += (size_t)NPTS*4;             // 2.77 MB
    float*          sw     = (float*)ws;          ws += (size_t)NPTS*4;             // 2.77 MB
    float*          scat   = (float*)ws;          ws += (size_t)TOT*CT*4;           // 16.78 MB
    int*            hist   = (int*)ws;            ws += (size_t)TOT*4;              // 0.26 MB
    int*            cursor = (int*)ws;            ws += (size_t)TOT*4;              // 0.26 MB
    double*         tf     = (double*)ws;         ws += (size_t)B_*N_*24*8;         // 4.6 KB
    unsigned short* WdB    = (unsigned short*)ws; ws += (size_t)NOP*CIN*2;          // 0.13 MB
    unsigned*       spk    = (unsigned*)featD;    // alias: featD consumed before scatter

    hipMemsetAsync(scat, 0, (size_t)TOT*CT*4, stream);
    hipMemsetAsync(hist, 0, (size_t)TOT*4, stream);
    prep_kernel<<<(NOP*CIN+255)/256, 256, 0, stream>>>(rots, trans, intrins, post_rots,
                                                       post_trans, Wd, tf, WdB);
    gemm_kernel<<<B_*N_*44, 256, 0, stream>>>(x, WdB, bd, featD, featB);
    sm_geom_kernel<<<B_*N_*176, 256, 0, stream>>>(featD, tf, w_arr, pk_arr, hist);
    scan_kernel<<<1, 1024, 0, stream>>>(hist, cursor);
    scatter_idx_kernel<<<(NPTS+255)/256, 256, 0, stream>>>(pk_arr, w_arr, cursor, spk, sw);
    gather_kernel<<<(NCHUNK+3)/4, 256, 0, stream>>>(spk, sw, cursor, featB, scat);
    transpose_k<<<B_*(NYY*NXX/64), 256, 0, stream>>>(scat, out);
}